// Round 5
// baseline (338.829 us; speedup 1.0000x reference)
//
#include <hip/hip_runtime.h>
#include <cstdint>
#include <cstddef>

typedef unsigned short u16;
typedef __attribute__((ext_vector_type(8))) short short8;
typedef __attribute__((ext_vector_type(4))) float v4f;

static constexpr size_t NN = (size_t)2048 * 2048;
#define N2 2048

typedef __attribute__((address_space(1))) const unsigned int guint;
typedef __attribute__((address_space(3))) unsigned int luint;

__device__ __forceinline__ u16 f2b(float f) {
  union { float f; uint32_t u; } v; v.f = f;
  uint32_t r = v.u + 0x7fffu + ((v.u >> 16) & 1u);
  return (u16)(r >> 16);
}
__device__ __forceinline__ uint2 pack4(const float* f) {
  uint2 u;
  u.x = (uint32_t)f2b(f[0]) | ((uint32_t)f2b(f[1]) << 16);
  u.y = (uint32_t)f2b(f[2]) | ((uint32_t)f2b(f[3]) << 16);
  return u;
}
__device__ __forceinline__ uint4 pack8(const float* f) {
  uint4 u;
  u.x = (uint32_t)f2b(f[0]) | ((uint32_t)f2b(f[1]) << 16);
  u.y = (uint32_t)f2b(f[2]) | ((uint32_t)f2b(f[3]) << 16);
  u.z = (uint32_t)f2b(f[4]) | ((uint32_t)f2b(f[5]) << 16);
  u.w = (uint32_t)f2b(f[6]) | ((uint32_t)f2b(f[7]) << 16);
  return u;
}

// ---------------------------------------------------------------------------
// K0: one pass over fp32 A[5][N][N]: softmax-weighted sums -> abf (bf16,
// row-major), bbt = b^T, a1t = a1^T (bf16 via LDS-tiled transpose).
// 32x32 tiles, 4096 blocks, 8.4 KB LDS -> high occupancy (was 4 blk/CU @64x64).
// ---------------------------------------------------------------------------
__global__ __launch_bounds__(256, 6) void conv_kernel(
    const float* __restrict__ A, const float* __restrict__ w1,
    const float* __restrict__ w2, const float* __restrict__ w3,
    u16* __restrict__ abf, u16* __restrict__ bbt, u16* __restrict__ a1t)
{
  __shared__ float lb[32][33];
  __shared__ float la[32][33];
  const int t = threadIdx.x;
  const int i0 = blockIdx.y * 32, j0 = blockIdx.x * 32;

  float s1[2][5], s2[2][5], s3[2][5];
  {
    const float* wsrc[3] = { w1, w2, w3 };
    float (*sdst[3])[5] = { s1, s2, s3 };
    for (int q = 0; q < 3; ++q)
      for (int c = 0; c < 2; ++c) {
        float v[5], m = -1e30f, sum = 0.f;
        for (int e = 0; e < 5; ++e) { v[e] = wsrc[q][c * 5 + e]; m = fmaxf(m, v[e]); }
        for (int e = 0; e < 5; ++e) { v[e] = expf(v[e] - m); sum += v[e]; }
        for (int e = 0; e < 5; ++e) sdst[q][c][e] = v[e] / sum;
      }
  }

  const int row = t >> 3;         // 0..31
  const int c4 = (t & 7) * 4;     // col base within tile
  float cst[2][4];                // a1 stash

  {
    float fa[5][4];
    for (int e = 0; e < 5; ++e) {
      float4 v = *(const float4*)(A + (size_t)e * NN + (size_t)(i0 + row) * N2 + (j0 + c4));
      fa[e][0] = v.x; fa[e][1] = v.y; fa[e][2] = v.z; fa[e][3] = v.w;
    }
    for (int c = 0; c < 2; ++c) {
      float av[4] = {0,0,0,0}, bv[4] = {0,0,0,0}, cv[4] = {0,0,0,0};
      for (int e = 0; e < 5; ++e)
        #pragma unroll
        for (int u = 0; u < 4; ++u) {
          av[u] += s1[c][e] * fa[e][u];
          bv[u] += s2[c][e] * fa[e][u];
          cv[u] += s3[c][e] * fa[e][u];
        }
      *(uint2*)(abf + (size_t)c * NN + (size_t)(i0 + row) * N2 + (j0 + c4)) = pack4(av);
      float* ldst = (c == 0) ? &lb[row][c4] : &la[row][c4];
      #pragma unroll
      for (int u = 0; u < 4; ++u) ldst[u] = bv[u];
      #pragma unroll
      for (int u = 0; u < 4; ++u) cst[c][u] = cv[u];
    }
  }
  __syncthreads();
  {
    float t0[4], t1[4];
    #pragma unroll
    for (int u = 0; u < 4; ++u) { t0[u] = lb[c4 + u][row]; t1[u] = la[c4 + u][row]; }
    *(uint2*)(bbt + 0 * NN + (size_t)(j0 + row) * N2 + (i0 + c4)) = pack4(t0);
    *(uint2*)(bbt + 1 * NN + (size_t)(j0 + row) * N2 + (i0 + c4)) = pack4(t1);
  }
  __syncthreads();
  #pragma unroll
  for (int u = 0; u < 4; ++u) { lb[row][c4 + u] = cst[0][u]; la[row][c4 + u] = cst[1][u]; }
  __syncthreads();
  {
    float t0[4], t1[4];
    #pragma unroll
    for (int u = 0; u < 4; ++u) { t0[u] = lb[c4 + u][row]; t1[u] = la[c4 + u][row]; }
    *(uint2*)(a1t + 0 * NN + (size_t)(j0 + row) * N2 + (i0 + c4)) = pack4(t0);
    *(uint2*)(a1t + 1 * NN + (size_t)(j0 + row) * N2 + (i0 + c4)) = pack4(t1);
  }
}

// ---------------------------------------------------------------------------
// bf16 MFMA GEMM, templated:
//   SCALE_A=false: A from bf16 Abf via global_load_lds (width 16).
//   SCALE_A=true:  A staged from fp32 Afp scaled by ci[k] with diag zeroed
//                  (fuses the _norm column-scaling), bf16-packed, ds_write_b128
//                  to the exact same swizzled LDS layout.
// B always bf16 K-contiguous via global_load_lds. C fp32 128x64 tile, BK=64.
// Epilogue additionally emits per-block column-sum partials csp[c][16][2048].
// ---------------------------------------------------------------------------
template<bool SCALE_A>
__global__ __launch_bounds__(256, 5) void gemm_kernel(
    const u16* __restrict__ Abf, const float* __restrict__ Afp,
    const float* __restrict__ ci, const u16* __restrict__ Btin,
    float* __restrict__ C, float* __restrict__ csp)
{
  const int c = blockIdx.z;
  const u16* Bc = Btin + (size_t)c * NN;
  float* Cc = C + (size_t)c * NN;
  const int m0 = blockIdx.y * 128, n0 = blockIdx.x * 64;
  const int t = threadIdx.x, w = t >> 6, lane = t & 63;
  const int quad = lane >> 4, r = lane & 15;
  __shared__ u16 As[128 * 64];
  __shared__ u16 Bs[64 * 64];

  v4f zero4 = { 0.f, 0.f, 0.f, 0.f };
  v4f acc[2][4];
  #pragma unroll
  for (int i = 0; i < 2; ++i)
    #pragma unroll
    for (int j = 0; j < 4; ++j) acc[i][j] = zero4;

  const int srow = lane >> 3;            // row within an 8-row chunk
  const int sgran = (lane & 7) ^ srow;   // swizzled k-granule

  for (int kt = 0; kt < 2048; kt += 64) {
    __syncthreads();
    #pragma unroll
    for (int i = 0; i < 2; ++i) {
      const int chunk = i * 4 + w;
      const u16* gb = Bc + (size_t)(n0 + chunk * 8 + srow) * N2 + kt + sgran * 8;
      __builtin_amdgcn_global_load_lds((guint*)gb, (luint*)(Bs + chunk * 512), 16, 0, 0);
    }
    if constexpr (!SCALE_A) {
      const u16* Ac = Abf + (size_t)c * NN;
      #pragma unroll
      for (int i = 0; i < 4; ++i) {
        const int chunk = i * 4 + w;
        const u16* ga = Ac + (size_t)(m0 + chunk * 8 + srow) * N2 + kt + sgran * 8;
        __builtin_amdgcn_global_load_lds((guint*)ga, (luint*)(As + chunk * 512), 16, 0, 0);
      }
    } else {
      const float* Ac = Afp + (size_t)c * NN;
      const float* civ = ci + c * N2 + kt + sgran * 8;
      float cv[8];
      { float4 c0 = *(const float4*)civ, c1 = *(const float4*)(civ + 4);
        cv[0]=c0.x; cv[1]=c0.y; cv[2]=c0.z; cv[3]=c0.w;
        cv[4]=c1.x; cv[5]=c1.y; cv[6]=c1.z; cv[7]=c1.w; }
      #pragma unroll
      for (int i = 0; i < 4; ++i) {
        const int chunk = i * 4 + w;
        const int grow = m0 + chunk * 8 + srow;
        const int gk = kt + sgran * 8;
        const float* ga = Ac + (size_t)grow * N2 + gk;
        float4 h0 = *(const float4*)ga, h1 = *(const float4*)(ga + 4);
        float f[8] = { h0.x, h0.y, h0.z, h0.w, h1.x, h1.y, h1.z, h1.w };
        #pragma unroll
        for (int u = 0; u < 8; ++u) {
          float v = f[u] * cv[u];
          f[u] = (gk + u == grow) ? 0.f : v;
        }
        *(uint4*)(As + chunk * 512 + lane * 8) = pack8(f);
      }
    }
    __syncthreads();
    #pragma unroll
    for (int ks = 0; ks < 2; ++ks) {
      const int sl = ((ks * 4 + quad) ^ (r & 7)) * 8;
      short8 af[2], bf[4];
      #pragma unroll
      for (int i = 0; i < 2; ++i)
        af[i] = *(const short8*)(As + (w * 32 + i * 16 + r) * 64 + sl);
      #pragma unroll
      for (int j = 0; j < 4; ++j)
        bf[j] = *(const short8*)(Bs + (j * 16 + r) * 64 + sl);
      #pragma unroll
      for (int i = 0; i < 2; ++i)
        #pragma unroll
        for (int j = 0; j < 4; ++j)
          acc[i][j] = __builtin_amdgcn_mfma_f32_16x16x32_bf16(af[i], bf[j], acc[i][j], 0, 0, 0);
    }
  }
  // Epilogue: C/D layout col=lane&15, row=quad*4+reg (m89-verified)
  #pragma unroll
  for (int i = 0; i < 2; ++i) {
    const int row = m0 + w * 32 + i * 16 + quad * 4;
    #pragma unroll
    for (int j = 0; j < 4; ++j) {
      const int col = n0 + j * 16 + r;
      #pragma unroll
      for (int g = 0; g < 4; ++g)
        Cc[(size_t)(row + g) * N2 + col] = acc[i][j][g];
    }
  }
  // Column-sum partials over this block's 128 rows for its 64 cols.
  float s[4];
  #pragma unroll
  for (int j = 0; j < 4; ++j) {
    s[j] = 0.f;
    #pragma unroll
    for (int i = 0; i < 2; ++i)
      #pragma unroll
      for (int g = 0; g < 4; ++g) s[j] += acc[i][j][g];
    s[j] += __shfl_xor(s[j], 16);
    s[j] += __shfl_xor(s[j], 32);
  }
  __syncthreads();                 // As no longer read by any wave
  float* csl = (float*)As;         // [4][64]
  if (quad == 0) {
    #pragma unroll
    for (int j = 0; j < 4; ++j) csl[w * 64 + j * 16 + r] = s[j];
  }
  __syncthreads();
  if (t < 64) {
    const float v = csl[t] + csl[64 + t] + csl[128 + t] + csl[192 + t];
    csp[((size_t)(c * 16) + blockIdx.y) * N2 + n0 + t] = v;
  }
}

// colinv[c][q] = (deg==0) ? 0 : 1/(deg+eps), deg = sum_s csp[c][s][q] - H[q][q]
__global__ void colinv_kernel(const float* __restrict__ H, const float* __restrict__ csp, float* __restrict__ ci)
{
  const int idx = blockIdx.x * 256 + threadIdx.x;  // [0, 4096)
  const int c = idx >> 11, q = idx & 2047;
  float cs = 0.f;
  #pragma unroll
  for (int s = 0; s < 16; ++s) cs += csp[((size_t)(c * 16) + s) * N2 + q];
  const float deg = cs - H[(size_t)c * NN + (size_t)q * N2 + q];
  ci[idx] = (deg == 0.f) ? 0.f : 1.f / (deg + 1e-8f);
}

// Xw = X @ gcn_weight (all fp32)
__global__ __launch_bounds__(256) void xw_kernel(const float* __restrict__ X, const float* __restrict__ W, float* __restrict__ Xw)
{
  const int t = threadIdx.x;
  const int k = t & 63;
  const int n = blockIdx.x * 4 + (t >> 6);
  float acc = 0.f;
  for (int m = 0; m < 256; ++m)
    acc += X[n * 256 + m] * W[m * 64 + k];
  Xw[n * 64 + k] = acc;
}

// ---------------------------------------------------------------------------
// T-partials: Tp[slab][c][i][k] = sum_{j in slab} H2[j][i]*Xw[j][k].
// Grid (32 i-tiles, 16 slabs of 128 rows, 2 c), 256 threads.
// ---------------------------------------------------------------------------
__global__ __launch_bounds__(256) void tpart_kernel(const float* __restrict__ H2, const float* __restrict__ Xw,
                                                    float* __restrict__ Tp)
{
  const int c = blockIdx.z, slab = blockIdx.y;
  const int i0 = blockIdx.x * 64;
  const int t = threadIdx.x, ti = t & 15, tk = t >> 4;
  const int col = t & 63, rgrp = t >> 6;
  __shared__ __attribute__((aligned(16))) float H2s[16][64];
  __shared__ __attribute__((aligned(16))) float Xws[16][64];
  const float* H2c = H2 + (size_t)c * NN;
  float acc[4][4] = {};

  for (int s = 0; s < 8; ++s) {
    const int jb = slab * 128 + s * 16;
    __syncthreads();
    #pragma unroll
    for (int rr = 0; rr < 4; ++rr) {
      const int jj = rr * 4 + rgrp;
      H2s[jj][col] = H2c[(size_t)(jb + jj) * N2 + i0 + col];
      Xws[jj][col] = Xw[(jb + jj) * 64 + col];
    }
    __syncthreads();
    #pragma unroll
    for (int jj = 0; jj < 16; ++jj) {
      const float4 h = *(const float4*)&H2s[jj][ti * 4];
      const float4 x = *(const float4*)&Xws[jj][tk * 4];
      const float ha[4] = { h.x, h.y, h.z, h.w };
      const float xa[4] = { x.x, x.y, x.z, x.w };
      #pragma unroll
      for (int a = 0; a < 4; ++a)
        #pragma unroll
        for (int b = 0; b < 4; ++b)
          acc[a][b] += ha[a] * xa[b];
    }
  }
  const size_t rbase = (size_t)(slab * 2 + c) * 2048 + i0;
  #pragma unroll
  for (int a = 0; a < 4; ++a) {
    float4 o; o.x = acc[a][0]; o.y = acc[a][1]; o.z = acc[a][2]; o.w = acc[a][3];
    *(float4*)&Tp[(rbase + ti * 4 + a) * 64 + tk * 4] = o;
  }
}

// out[i][c*64+k] = relu( dinv * (T - H2[i][i]*Xw[i][k] + Xw[i][k]) ), fp32
__global__ void epilogue_kernel(const float* __restrict__ Tp, const float* __restrict__ cspb,
                                const float* __restrict__ H2, const float* __restrict__ Xw,
                                float* __restrict__ out)
{
  const int idx = blockIdx.x * 256 + threadIdx.x;
  const int k = idx & 63;
  const int c = (idx >> 6) & 1;
  const int i = idx >> 7;
  float T = 0.f, cs = 0.f;
  #pragma unroll
  for (int s = 0; s < 16; ++s) {
    T  += Tp[((size_t)(s * 2 + c) * 2048 + i) * 64 + k];
    cs += cspb[((size_t)(c * 16) + s) * N2 + i];
  }
  const float hd = H2[(size_t)c * NN + (size_t)i * N2 + i];
  const float xw = Xw[i * 64 + k];
  const float deg = cs - hd + 1.0f;  // add=True: diag set to 1 contributes +1
  const float dinv = (deg == 0.f) ? 0.f : 1.f / (deg + 1e-8f);
  float v = dinv * (T - hd * xw + xw);
  v = v > 0.f ? v : 0.f;
  out[(size_t)i * 128 + c * 64 + k] = v;
}

// ---------------------------------------------------------------------------
// Workspace layout (bytes), ~85 MB, all reads preceded by writes:
//   abf   @ 0          (16.78 MB bf16)  -- dead after GEMM1
//   bbt   @ 16777216   (16.78 MB bf16)  -- dead after GEMM1
//   a1t   @ 33554432   (16.78 MB bf16)
//   H     @ 50331648   (33.55 MB fp32)  -- dead after GEMM2 (read as scaled A)
//   Xw    @ 83886080   (0.52 MB fp32)
//   cspa  @ 84410368   (256 KB)  gemm1 colsum partials
//   cspb  @ 84672512   (256 KB)  gemm2 colsum partials
//   ci1   @ 84934656   (16 KB)          -- end 84950784
//   H2    @ 0          (33.55 MB fp32, over abf+bbt)
//   Tp    @ 50331648   (33.55 MB fp32, over H)
// ---------------------------------------------------------------------------
extern "C" void kernel_launch(void* const* d_in, const int* in_sizes, int n_in,
                              void* d_out, int out_size, void* d_ws, size_t ws_size,
                              hipStream_t stream) {
  const float* A  = (const float*)d_in[0];
  const float* X  = (const float*)d_in[1];
  const float* w1 = (const float*)d_in[2];
  const float* w2 = (const float*)d_in[3];
  const float* w3 = (const float*)d_in[4];
  const float* W  = (const float*)d_in[5];
  float* out = (float*)d_out;
  char* ws = (char*)d_ws;

  u16*   abf  = (u16*)(ws + 0);
  u16*   bbt  = (u16*)(ws + 16777216);
  u16*   a1t  = (u16*)(ws + 33554432);
  float* H    = (float*)(ws + 50331648);
  float* Xw   = (float*)(ws + 83886080);
  float* cspa = (float*)(ws + 84410368);
  float* cspb = (float*)(ws + 84672512);
  float* ci1  = (float*)(ws + 84934656);
  float* H2   = (float*)(ws + 0);
  float* Tp   = (float*)(ws + 50331648);

  conv_kernel<<<dim3(64, 64), 256, 0, stream>>>(A, w1, w2, w3, abf, bbt, a1t);
  xw_kernel<<<512, 256, 0, stream>>>(X, W, Xw);
  gemm_kernel<false><<<dim3(32, 16, 2), 256, 0, stream>>>(abf, nullptr, nullptr, bbt, H, cspa);
  colinv_kernel<<<16, 256, 0, stream>>>(H, cspa, ci1);
  gemm_kernel<true><<<dim3(32, 16, 2), 256, 0, stream>>>(nullptr, H, ci1, a1t, H2, cspb);
  tpart_kernel<<<dim3(32, 16, 2), 256, 0, stream>>>(H2, Xw, Tp);
  epilogue_kernel<<<1024, 256, 0, stream>>>(Tp, cspb, H2, Xw, out);
}

// Round 6
// 298.267 us; speedup vs baseline: 1.1360x; 1.1360x over previous
//
#include <hip/hip_runtime.h>
#include <cstdint>
#include <cstddef>

typedef unsigned short u16;
typedef __attribute__((ext_vector_type(8))) short short8;
typedef __attribute__((ext_vector_type(4))) float v4f;

static constexpr size_t NN = (size_t)2048 * 2048;
#define N2 2048

typedef __attribute__((address_space(1))) const unsigned int guint;
typedef __attribute__((address_space(3))) unsigned int luint;

__device__ __forceinline__ float b2f_bits(uint32_t hi) { union { uint32_t u; float f; } v; v.u = hi; return v.f; }
__device__ __forceinline__ float b2f(u16 x) { return b2f_bits((uint32_t)x << 16); }
__device__ __forceinline__ u16 f2b(float f) {
  union { float f; uint32_t u; } v; v.f = f;
  uint32_t r = v.u + 0x7fffu + ((v.u >> 16) & 1u);
  return (u16)(r >> 16);
}
__device__ __forceinline__ uint2 pack4(const float* f) {
  uint2 u;
  u.x = (uint32_t)f2b(f[0]) | ((uint32_t)f2b(f[1]) << 16);
  u.y = (uint32_t)f2b(f[2]) | ((uint32_t)f2b(f[3]) << 16);
  return u;
}
__device__ __forceinline__ uint4 pack8(const float* f) {
  uint4 u;
  u.x = (uint32_t)f2b(f[0]) | ((uint32_t)f2b(f[1]) << 16);
  u.y = (uint32_t)f2b(f[2]) | ((uint32_t)f2b(f[3]) << 16);
  u.z = (uint32_t)f2b(f[4]) | ((uint32_t)f2b(f[5]) << 16);
  u.w = (uint32_t)f2b(f[6]) | ((uint32_t)f2b(f[7]) << 16);
  return u;
}

// ---------------------------------------------------------------------------
// K0: one pass over fp32 A[5][N][N]: softmax-weighted sums -> abf (bf16,
// row-major), bbt = b^T, a1t = a1^T (bf16 via LDS-tiled transpose).
// 32x32 tiles, 4096 blocks, 8.4 KB LDS.
// ---------------------------------------------------------------------------
__global__ __launch_bounds__(256, 6) void conv_kernel(
    const float* __restrict__ A, const float* __restrict__ w1,
    const float* __restrict__ w2, const float* __restrict__ w3,
    u16* __restrict__ abf, u16* __restrict__ bbt, u16* __restrict__ a1t)
{
  __shared__ float lb[32][33];
  __shared__ float la[32][33];
  const int t = threadIdx.x;
  const int i0 = blockIdx.y * 32, j0 = blockIdx.x * 32;

  float s1[2][5], s2[2][5], s3[2][5];
  {
    const float* wsrc[3] = { w1, w2, w3 };
    float (*sdst[3])[5] = { s1, s2, s3 };
    for (int q = 0; q < 3; ++q)
      for (int c = 0; c < 2; ++c) {
        float v[5], m = -1e30f, sum = 0.f;
        for (int e = 0; e < 5; ++e) { v[e] = wsrc[q][c * 5 + e]; m = fmaxf(m, v[e]); }
        for (int e = 0; e < 5; ++e) { v[e] = expf(v[e] - m); sum += v[e]; }
        for (int e = 0; e < 5; ++e) sdst[q][c][e] = v[e] / sum;
      }
  }

  const int row = t >> 3;         // 0..31
  const int c4 = (t & 7) * 4;     // col base within tile
  float cst[2][4];                // a1 stash

  {
    float fa[5][4];
    for (int e = 0; e < 5; ++e) {
      float4 v = *(const float4*)(A + (size_t)e * NN + (size_t)(i0 + row) * N2 + (j0 + c4));
      fa[e][0] = v.x; fa[e][1] = v.y; fa[e][2] = v.z; fa[e][3] = v.w;
    }
    for (int c = 0; c < 2; ++c) {
      float av[4] = {0,0,0,0}, bv[4] = {0,0,0,0}, cv[4] = {0,0,0,0};
      for (int e = 0; e < 5; ++e)
        #pragma unroll
        for (int u = 0; u < 4; ++u) {
          av[u] += s1[c][e] * fa[e][u];
          bv[u] += s2[c][e] * fa[e][u];
          cv[u] += s3[c][e] * fa[e][u];
        }
      *(uint2*)(abf + (size_t)c * NN + (size_t)(i0 + row) * N2 + (j0 + c4)) = pack4(av);
      float* ldst = (c == 0) ? &lb[row][c4] : &la[row][c4];
      #pragma unroll
      for (int u = 0; u < 4; ++u) ldst[u] = bv[u];
      #pragma unroll
      for (int u = 0; u < 4; ++u) cst[c][u] = cv[u];
    }
  }
  __syncthreads();
  {
    float t0[4], t1[4];
    #pragma unroll
    for (int u = 0; u < 4; ++u) { t0[u] = lb[c4 + u][row]; t1[u] = la[c4 + u][row]; }
    *(uint2*)(bbt + 0 * NN + (size_t)(j0 + row) * N2 + (i0 + c4)) = pack4(t0);
    *(uint2*)(bbt + 1 * NN + (size_t)(j0 + row) * N2 + (i0 + c4)) = pack4(t1);
  }
  __syncthreads();
  #pragma unroll
  for (int u = 0; u < 4; ++u) { lb[row][c4 + u] = cst[0][u]; la[row][c4 + u] = cst[1][u]; }
  __syncthreads();
  {
    float t0[4], t1[4];
    #pragma unroll
    for (int u = 0; u < 4; ++u) { t0[u] = lb[c4 + u][row]; t1[u] = la[c4 + u][row]; }
    *(uint2*)(a1t + 0 * NN + (size_t)(j0 + row) * N2 + (i0 + c4)) = pack4(t0);
    *(uint2*)(a1t + 1 * NN + (size_t)(j0 + row) * N2 + (i0 + c4)) = pack4(t1);
  }
}

// ---------------------------------------------------------------------------
// bf16 MFMA GEMM (glds staging both operands, r4-proven): C[c] = A[c]@B[c].
// A [M][K] bf16 row-major, Bt [N][K] bf16 K-contiguous. 128x64 tile, BK=64.
// Outputs: Cb (bf16), per-block column-sum partials csp[c][16][2048] (fp32,
// from registers pre-rounding), diag[c][2048] (fp32 diagonal, pre-rounding).
// ---------------------------------------------------------------------------
__global__ __launch_bounds__(256, 5) void gemm_kernel(
    const u16* __restrict__ Ain, const u16* __restrict__ Btin,
    u16* __restrict__ Cb, float* __restrict__ csp, float* __restrict__ diag)
{
  const int c = blockIdx.z;
  const u16* Ac = Ain + (size_t)c * NN;
  const u16* Bc = Btin + (size_t)c * NN;
  u16* Cc = Cb + (size_t)c * NN;
  const int m0 = blockIdx.y * 128, n0 = blockIdx.x * 64;
  const int t = threadIdx.x, w = t >> 6, lane = t & 63;
  const int quad = lane >> 4, r = lane & 15;
  __shared__ u16 As[128 * 64];
  __shared__ u16 Bs[64 * 64];

  v4f zero4 = { 0.f, 0.f, 0.f, 0.f };
  v4f acc[2][4];
  #pragma unroll
  for (int i = 0; i < 2; ++i)
    #pragma unroll
    for (int j = 0; j < 4; ++j) acc[i][j] = zero4;

  const int srow = lane >> 3;            // row within an 8-row chunk
  const int sgran = (lane & 7) ^ srow;   // swizzled k-granule

  for (int kt = 0; kt < 2048; kt += 64) {
    __syncthreads();
    #pragma unroll
    for (int i = 0; i < 4; ++i) {
      const int chunk = i * 4 + w;
      const u16* ga = Ac + (size_t)(m0 + chunk * 8 + srow) * N2 + kt + sgran * 8;
      __builtin_amdgcn_global_load_lds((guint*)ga, (luint*)(As + chunk * 512), 16, 0, 0);
    }
    #pragma unroll
    for (int i = 0; i < 2; ++i) {
      const int chunk = i * 4 + w;
      const u16* gb = Bc + (size_t)(n0 + chunk * 8 + srow) * N2 + kt + sgran * 8;
      __builtin_amdgcn_global_load_lds((guint*)gb, (luint*)(Bs + chunk * 512), 16, 0, 0);
    }
    __syncthreads();
    #pragma unroll
    for (int ks = 0; ks < 2; ++ks) {
      const int sl = ((ks * 4 + quad) ^ (r & 7)) * 8;
      short8 af[2], bf[4];
      #pragma unroll
      for (int i = 0; i < 2; ++i)
        af[i] = *(const short8*)(As + (w * 32 + i * 16 + r) * 64 + sl);
      #pragma unroll
      for (int j = 0; j < 4; ++j)
        bf[j] = *(const short8*)(Bs + (j * 16 + r) * 64 + sl);
      #pragma unroll
      for (int i = 0; i < 2; ++i)
        #pragma unroll
        for (int j = 0; j < 4; ++j)
          acc[i][j] = __builtin_amdgcn_mfma_f32_16x16x32_bf16(af[i], bf[j], acc[i][j], 0, 0, 0);
    }
  }
  // Epilogue. C/D layout: col=lane&15, row=quad*4+reg (m89-verified).
  #pragma unroll
  for (int i = 0; i < 2; ++i) {
    const int row = m0 + w * 32 + i * 16 + quad * 4;
    #pragma unroll
    for (int j = 0; j < 4; ++j) {
      const int col = n0 + j * 16 + r;
      #pragma unroll
      for (int g = 0; g < 4; ++g)
        Cc[(size_t)(row + g) * N2 + col] = f2b(acc[i][j][g]);
    }
  }
  // Diagonal (fp32, pre-rounding). Only tiles the diagonal crosses.
  if ((int)(blockIdx.x >> 1) == (int)blockIdx.y) {
    #pragma unroll
    for (int i = 0; i < 2; ++i) {
      const int row = m0 + w * 32 + i * 16 + quad * 4;
      #pragma unroll
      for (int j = 0; j < 4; ++j) {
        const int col = n0 + j * 16 + r;
        #pragma unroll
        for (int g = 0; g < 4; ++g)
          if (row + g == col) diag[c * N2 + col] = acc[i][j][g];
      }
    }
  }
  // Column-sum partials over this block's 128 rows for its 64 cols.
  float s[4];
  #pragma unroll
  for (int j = 0; j < 4; ++j) {
    s[j] = 0.f;
    #pragma unroll
    for (int i = 0; i < 2; ++i)
      #pragma unroll
      for (int g = 0; g < 4; ++g) s[j] += acc[i][j][g];
    s[j] += __shfl_xor(s[j], 16);
    s[j] += __shfl_xor(s[j], 32);
  }
  __syncthreads();                 // LDS no longer read
  float* csl = (float*)As;         // [4][64]
  if (quad == 0) {
    #pragma unroll
    for (int j = 0; j < 4; ++j) csl[w * 64 + j * 16 + r] = s[j];
  }
  __syncthreads();
  if (t < 64) {
    const float v = csl[t] + csl[64 + t] + csl[128 + t] + csl[192 + t];
    csp[((size_t)(c * 16) + blockIdx.y) * N2 + n0 + t] = v;
  }
}

// colinv[c][q] = (deg==0) ? 0 : 1/(deg+eps), deg = sum_s csp[c][s][q] - diag
__global__ void colinv_kernel(const float* __restrict__ csp, const float* __restrict__ diag, float* __restrict__ ci)
{
  const int idx = blockIdx.x * 256 + threadIdx.x;  // [0, 4096)
  const int c = idx >> 11, q = idx & 2047;
  float cs = 0.f;
  #pragma unroll
  for (int s = 0; s < 16; ++s) cs += csp[((size_t)(c * 16) + s) * N2 + q];
  const float deg = cs - diag[idx];
  ci[idx] = (deg == 0.f) ? 0.f : 1.f / (deg + 1e-8f);
}

// Hn[p][q] = bf16( p==q ? 0 : ci[q]*H[p][q] ), H bf16 in, bf16 out
__global__ __launch_bounds__(256) void scale_kernel(const u16* __restrict__ H, const float* __restrict__ ci, u16* __restrict__ Hn)
{
  const int idx = blockIdx.x * 256 + threadIdx.x;
  const int q0 = (idx & 255) * 8;
  const int p = (idx >> 8) & 2047;
  const int c = idx >> 19;
  const u16* src = H + (size_t)c * NN + (size_t)p * N2 + q0;
  const float* cv = ci + c * N2 + q0;
  uint4 hu = *(const uint4*)src;
  float h[8];
  h[0] = b2f_bits(hu.x << 16); h[1] = b2f_bits(hu.x & 0xffff0000u);
  h[2] = b2f_bits(hu.y << 16); h[3] = b2f_bits(hu.y & 0xffff0000u);
  h[4] = b2f_bits(hu.z << 16); h[5] = b2f_bits(hu.z & 0xffff0000u);
  h[6] = b2f_bits(hu.w << 16); h[7] = b2f_bits(hu.w & 0xffff0000u);
  float f[8];
  #pragma unroll
  for (int u = 0; u < 8; ++u) {
    float v = h[u] * cv[u];
    f[u] = (q0 + u == p) ? 0.f : v;
  }
  *(uint4*)(Hn + (size_t)c * NN + (size_t)p * N2 + q0) = pack8(f);
}

// Xw = X @ gcn_weight (all fp32)
__global__ __launch_bounds__(256) void xw_kernel(const float* __restrict__ X, const float* __restrict__ W, float* __restrict__ Xw)
{
  const int t = threadIdx.x;
  const int k = t & 63;
  const int n = blockIdx.x * 4 + (t >> 6);
  float acc = 0.f;
  for (int m = 0; m < 256; ++m)
    acc += X[n * 256 + m] * W[m * 64 + k];
  Xw[n * 64 + k] = acc;
}

// ---------------------------------------------------------------------------
// T-partials: Tp[slab][c][i][k] = sum_{j in slab} H2[j][i]*Xw[j][k], H2 bf16.
// Grid (32 i-tiles, 16 slabs of 128 rows, 2 c), 256 threads.
// ---------------------------------------------------------------------------
__global__ __launch_bounds__(256) void tpart_kernel(const u16* __restrict__ H2b, const float* __restrict__ Xw,
                                                    float* __restrict__ Tp)
{
  const int c = blockIdx.z, slab = blockIdx.y;
  const int i0 = blockIdx.x * 64;
  const int t = threadIdx.x, ti = t & 15, tk = t >> 4;
  const int col = t & 63, rgrp = t >> 6;
  __shared__ __attribute__((aligned(16))) float H2s[16][64];
  __shared__ __attribute__((aligned(16))) float Xws[16][64];
  const u16* H2c = H2b + (size_t)c * NN;
  float acc[4][4] = {};

  for (int s = 0; s < 8; ++s) {
    const int jb = slab * 128 + s * 16;
    __syncthreads();
    #pragma unroll
    for (int rr = 0; rr < 4; ++rr) {
      const int jj = rr * 4 + rgrp;
      H2s[jj][col] = b2f(H2c[(size_t)(jb + jj) * N2 + i0 + col]);
      Xws[jj][col] = Xw[(jb + jj) * 64 + col];
    }
    __syncthreads();
    #pragma unroll
    for (int jj = 0; jj < 16; ++jj) {
      const float4 h = *(const float4*)&H2s[jj][ti * 4];
      const float4 x = *(const float4*)&Xws[jj][tk * 4];
      const float ha[4] = { h.x, h.y, h.z, h.w };
      const float xa[4] = { x.x, x.y, x.z, x.w };
      #pragma unroll
      for (int a = 0; a < 4; ++a)
        #pragma unroll
        for (int b = 0; b < 4; ++b)
          acc[a][b] += ha[a] * xa[b];
    }
  }
  const size_t rbase = (size_t)(slab * 2 + c) * 2048 + i0;
  #pragma unroll
  for (int a = 0; a < 4; ++a) {
    float4 o; o.x = acc[a][0]; o.y = acc[a][1]; o.z = acc[a][2]; o.w = acc[a][3];
    *(float4*)&Tp[(rbase + ti * 4 + a) * 64 + tk * 4] = o;
  }
}

// out[i][c*64+k] = relu( dinv * (T - H2diag[i]*Xw[i][k] + Xw[i][k]) ), fp32
__global__ void epilogue_kernel(const float* __restrict__ Tp, const float* __restrict__ cspb,
                                const float* __restrict__ diag2, const float* __restrict__ Xw,
                                float* __restrict__ out)
{
  const int idx = blockIdx.x * 256 + threadIdx.x;
  const int k = idx & 63;
  const int c = (idx >> 6) & 1;
  const int i = idx >> 7;
  float T = 0.f, cs = 0.f;
  #pragma unroll
  for (int s = 0; s < 16; ++s) {
    T  += Tp[((size_t)(s * 2 + c) * 2048 + i) * 64 + k];
    cs += cspb[((size_t)(c * 16) + s) * N2 + i];
  }
  const float hd = diag2[c * N2 + i];
  const float xw = Xw[i * 64 + k];
  const float deg = cs - hd + 1.0f;  // add=True: diag set to 1 contributes +1
  const float dinv = (deg == 0.f) ? 0.f : 1.f / (deg + 1e-8f);
  float v = dinv * (T - hd * xw + xw);
  v = v > 0.f ? v : 0.f;
  out[(size_t)i * 128 + c * 64 + k] = v;
}

// ---------------------------------------------------------------------------
// Workspace layout (bytes), ~85 MB, all reads preceded by writes:
//   abf   @ 0          (16.78 MB bf16)  -- dead after gemm1
//   bbt   @ 16777216   (16.78 MB bf16)  -- dead after gemm1
//   a1t   @ 33554432   (16.78 MB bf16)  -- dead after gemm2
//   Hbf   @ 50331648   (16.78 MB bf16)  -- dead after scale
//   Hn    @ 67108864   (16.78 MB bf16)  -- dead after gemm2
//   Xw    @ 83886080   (0.52 MB fp32)
//   cspa  @ 84410368   (256 KB)
//   cspb  @ 84672512   (256 KB)
//   diag1 @ 84934656   (16 KB)
//   diag2 @ 84951040   (16 KB)
//   ci1   @ 84967424   (16 KB)          -- end 84983808
//   H2bf  @ 0          (16.78 MB bf16, over abf; written by gemm2)
//   Tp    @ 16777216   (33.55 MB fp32, over bbt+a1t; written by tpart)
// ---------------------------------------------------------------------------
extern "C" void kernel_launch(void* const* d_in, const int* in_sizes, int n_in,
                              void* d_out, int out_size, void* d_ws, size_t ws_size,
                              hipStream_t stream) {
  const float* A  = (const float*)d_in[0];
  const float* X  = (const float*)d_in[1];
  const float* w1 = (const float*)d_in[2];
  const float* w2 = (const float*)d_in[3];
  const float* w3 = (const float*)d_in[4];
  const float* W  = (const float*)d_in[5];
  float* out = (float*)d_out;
  char* ws = (char*)d_ws;

  u16*   abf   = (u16*)(ws + 0);
  u16*   bbt   = (u16*)(ws + 16777216);
  u16*   a1t   = (u16*)(ws + 33554432);
  u16*   Hbf   = (u16*)(ws + 50331648);
  u16*   Hn    = (u16*)(ws + 67108864);
  float* Xw    = (float*)(ws + 83886080);
  float* cspa  = (float*)(ws + 84410368);
  float* cspb  = (float*)(ws + 84672512);
  float* diag1 = (float*)(ws + 84934656);
  float* diag2 = (float*)(ws + 84951040);
  float* ci1   = (float*)(ws + 84967424);
  u16*   H2bf  = (u16*)(ws + 0);
  float* Tp    = (float*)(ws + 16777216);

  conv_kernel<<<dim3(64, 64), 256, 0, stream>>>(A, w1, w2, w3, abf, bbt, a1t);
  xw_kernel<<<512, 256, 0, stream>>>(X, W, Xw);
  gemm_kernel<<<dim3(32, 16, 2), 256, 0, stream>>>(abf, bbt, Hbf, cspa, diag1);
  colinv_kernel<<<16, 256, 0, stream>>>(cspa, diag1, ci1);
  scale_kernel<<<4096, 256, 0, stream>>>(Hbf, ci1, Hn);
  gemm_kernel<<<dim3(32, 16, 2), 256, 0, stream>>>(Hn, a1t, H2bf, cspb, diag2);
  tpart_kernel<<<dim3(32, 16, 2), 256, 0, stream>>>(H2bf, Xw, Tp);
  epilogue_kernel<<<1024, 256, 0, stream>>>(Tp, cspb, diag2, Xw, out);
}

// Round 9
// 266.512 us; speedup vs baseline: 1.2713x; 1.1191x over previous
//
#include <hip/hip_runtime.h>
#include <cstdint>
#include <cstddef>

typedef unsigned short u16;
typedef __attribute__((ext_vector_type(8))) short short8;
typedef __attribute__((ext_vector_type(4))) float v4f;

static constexpr size_t NN = (size_t)2048 * 2048;
#define N2 2048

typedef __attribute__((address_space(1))) const unsigned int guint;
typedef __attribute__((address_space(3))) unsigned int luint;

__device__ __forceinline__ float b2f_bits(uint32_t hi) { union { uint32_t u; float f; } v; v.u = hi; return v.f; }
__device__ __forceinline__ float b2f(u16 x) { return b2f_bits((uint32_t)x << 16); }
__device__ __forceinline__ u16 f2b(float f) {
  union { float f; uint32_t u; } v; v.f = f;
  uint32_t r = v.u + 0x7fffu + ((v.u >> 16) & 1u);
  return (u16)(r >> 16);
}
__device__ __forceinline__ uint2 pack4(const float* f) {
  uint2 u;
  u.x = (uint32_t)f2b(f[0]) | ((uint32_t)f2b(f[1]) << 16);
  u.y = (uint32_t)f2b(f[2]) | ((uint32_t)f2b(f[3]) << 16);
  return u;
}
__device__ __forceinline__ uint4 pack8(const float* f) {
  uint4 u;
  u.x = (uint32_t)f2b(f[0]) | ((uint32_t)f2b(f[1]) << 16);
  u.y = (uint32_t)f2b(f[2]) | ((uint32_t)f2b(f[3]) << 16);
  u.z = (uint32_t)f2b(f[4]) | ((uint32_t)f2b(f[5]) << 16);
  u.w = (uint32_t)f2b(f[6]) | ((uint32_t)f2b(f[7]) << 16);
  return u;
}

// ---------------------------------------------------------------------------
// K0: one pass over fp32 A[5][N][N]: softmax-weighted sums -> abf (bf16,
// row-major), bbt = b^T, a1t = a1^T (bf16 via LDS-tiled transpose).
// 32x32 tiles, 4096 blocks. Blocks with by<8 additionally compute
// Xwt[k][n] = bf16( (X @ W)[n][k] )  (the tiny 2048x256x64 GEMM).
// ---------------------------------------------------------------------------
__global__ __launch_bounds__(256, 6) void conv_kernel(
    const float* __restrict__ A, const float* __restrict__ w1,
    const float* __restrict__ w2, const float* __restrict__ w3,
    const float* __restrict__ X, const float* __restrict__ W,
    u16* __restrict__ abf, u16* __restrict__ bbt, u16* __restrict__ a1t,
    u16* __restrict__ Xwt)
{
  __shared__ float lb[32][33];
  __shared__ float la[32][33];
  const int t = threadIdx.x;
  const int i0 = blockIdx.y * 32, j0 = blockIdx.x * 32;

  float s1[2][5], s2[2][5], s3[2][5];
  {
    const float* wsrc[3] = { w1, w2, w3 };
    float (*sdst[3])[5] = { s1, s2, s3 };
    for (int q = 0; q < 3; ++q)
      for (int c = 0; c < 2; ++c) {
        float v[5], m = -1e30f, sum = 0.f;
        for (int e = 0; e < 5; ++e) { v[e] = wsrc[q][c * 5 + e]; m = fmaxf(m, v[e]); }
        for (int e = 0; e < 5; ++e) { v[e] = expf(v[e] - m); sum += v[e]; }
        for (int e = 0; e < 5; ++e) sdst[q][c][e] = v[e] / sum;
      }
  }

  const int row = t >> 3;         // 0..31
  const int c4 = (t & 7) * 4;     // col base within tile
  float cst[2][4];                // a1 stash

  {
    float fa[5][4];
    for (int e = 0; e < 5; ++e) {
      float4 v = *(const float4*)(A + (size_t)e * NN + (size_t)(i0 + row) * N2 + (j0 + c4));
      fa[e][0] = v.x; fa[e][1] = v.y; fa[e][2] = v.z; fa[e][3] = v.w;
    }
    for (int c = 0; c < 2; ++c) {
      float av[4] = {0,0,0,0}, bv[4] = {0,0,0,0}, cv[4] = {0,0,0,0};
      for (int e = 0; e < 5; ++e)
        #pragma unroll
        for (int u = 0; u < 4; ++u) {
          av[u] += s1[c][e] * fa[e][u];
          bv[u] += s2[c][e] * fa[e][u];
          cv[u] += s3[c][e] * fa[e][u];
        }
      *(uint2*)(abf + (size_t)c * NN + (size_t)(i0 + row) * N2 + (j0 + c4)) = pack4(av);
      float* ldst = (c == 0) ? &lb[row][c4] : &la[row][c4];
      #pragma unroll
      for (int u = 0; u < 4; ++u) ldst[u] = bv[u];
      #pragma unroll
      for (int u = 0; u < 4; ++u) cst[c][u] = cv[u];
    }
  }
  __syncthreads();
  {
    float t0[4], t1[4];
    #pragma unroll
    for (int u = 0; u < 4; ++u) { t0[u] = lb[c4 + u][row]; t1[u] = la[c4 + u][row]; }
    *(uint2*)(bbt + 0 * NN + (size_t)(j0 + row) * N2 + (i0 + c4)) = pack4(t0);
    *(uint2*)(bbt + 1 * NN + (size_t)(j0 + row) * N2 + (i0 + c4)) = pack4(t1);
  }
  __syncthreads();
  #pragma unroll
  for (int u = 0; u < 4; ++u) { lb[row][c4 + u] = cst[0][u]; la[row][c4 + u] = cst[1][u]; }
  __syncthreads();
  {
    float t0[4], t1[4];
    #pragma unroll
    for (int u = 0; u < 4; ++u) { t0[u] = lb[c4 + u][row]; t1[u] = la[c4 + u][row]; }
    *(uint2*)(a1t + 0 * NN + (size_t)(j0 + row) * N2 + (i0 + c4)) = pack4(t0);
    *(uint2*)(a1t + 1 * NN + (size_t)(j0 + row) * N2 + (i0 + c4)) = pack4(t1);
  }
  // Folded Xw^T compute: 512 blocks x 4 rows = 2048 rows.
  if (blockIdx.y < 8) {
    const int n = (int)(blockIdx.y * 64 + blockIdx.x) * 4 + (t >> 6);
    const int k = t & 63;
    float acc = 0.f;
    for (int m = 0; m < 256; ++m)
      acc += X[n * 256 + m] * W[m * 64 + k];
    Xwt[(size_t)k * N2 + n] = f2b(acc);
  }
}

// ---------------------------------------------------------------------------
// bf16 MFMA GEMM (glds staging, 128x64 tile, BK=64, 256 thr). C = A@B with
// A [M][K] bf16 row-major, Bt [N][K] bf16 K-contiguous.
// Emits: column-sum partials csp[c][16][2048] (fp32, pre-rounding) and
// diag[c][2048] (fp32 diagonal). Output:
//   TOUT=false: Cout = bf16 C row-major [M][N-global].
//   TOUT=true:  Cout = bf16 C^T (rows = cols of C), via in-LDS transpose.
// ---------------------------------------------------------------------------
template<bool TOUT>
__global__ __launch_bounds__(256, 5) void gemm_kernel(
    const u16* __restrict__ Ain, const u16* __restrict__ Btin,
    u16* __restrict__ Cout, float* __restrict__ csp, float* __restrict__ diag)
{
  const int c = blockIdx.z;
  const u16* Ac = Ain + (size_t)c * NN;
  const u16* Bc = Btin + (size_t)c * NN;
  const int m0 = blockIdx.y * 128, n0 = blockIdx.x * 64;
  const int t = threadIdx.x, w = t >> 6, lane = t & 63;
  const int quad = lane >> 4, r = lane & 15;
  __shared__ u16 SM[128 * 64 + 64 * 64];   // As | Bs (24 KB)
  u16* As = SM;
  u16* Bs = SM + 128 * 64;

  v4f zero4 = { 0.f, 0.f, 0.f, 0.f };
  v4f acc[2][4];
  #pragma unroll
  for (int i = 0; i < 2; ++i)
    #pragma unroll
    for (int j = 0; j < 4; ++j) acc[i][j] = zero4;

  const int srow = lane >> 3;            // row within an 8-row chunk
  const int sgran = (lane & 7) ^ srow;   // swizzled k-granule

  for (int kt = 0; kt < 2048; kt += 64) {
    __syncthreads();
    #pragma unroll
    for (int i = 0; i < 4; ++i) {
      const int chunk = i * 4 + w;
      const u16* ga = Ac + (size_t)(m0 + chunk * 8 + srow) * N2 + kt + sgran * 8;
      __builtin_amdgcn_global_load_lds((guint*)ga, (luint*)(As + chunk * 512), 16, 0, 0);
    }
    #pragma unroll
    for (int i = 0; i < 2; ++i) {
      const int chunk = i * 4 + w;
      const u16* gb = Bc + (size_t)(n0 + chunk * 8 + srow) * N2 + kt + sgran * 8;
      __builtin_amdgcn_global_load_lds((guint*)gb, (luint*)(Bs + chunk * 512), 16, 0, 0);
    }
    __syncthreads();
    #pragma unroll
    for (int ks = 0; ks < 2; ++ks) {
      const int sl = ((ks * 4 + quad) ^ (r & 7)) * 8;
      short8 af[2], bf[4];
      #pragma unroll
      for (int i = 0; i < 2; ++i)
        af[i] = *(const short8*)(As + (w * 32 + i * 16 + r) * 64 + sl);
      #pragma unroll
      for (int j = 0; j < 4; ++j)
        bf[j] = *(const short8*)(Bs + (j * 16 + r) * 64 + sl);
      #pragma unroll
      for (int i = 0; i < 2; ++i)
        #pragma unroll
        for (int j = 0; j < 4; ++j)
          acc[i][j] = __builtin_amdgcn_mfma_f32_16x16x32_bf16(af[i], bf[j], acc[i][j], 0, 0, 0);
    }
  }
  // C/D layout: col=lane&15, row=quad*4+reg (m89-verified).
  // Diagonal (fp32, pre-rounding).
  if ((int)(blockIdx.x >> 1) == (int)blockIdx.y) {
    #pragma unroll
    for (int i = 0; i < 2; ++i) {
      const int rowg = m0 + w * 32 + i * 16 + quad * 4;
      #pragma unroll
      for (int j = 0; j < 4; ++j) {
        const int colg = n0 + j * 16 + r;
        #pragma unroll
        for (int g = 0; g < 4; ++g)
          if (rowg + g == colg) diag[c * N2 + colg] = acc[i][j][g];
      }
    }
  }
  if constexpr (!TOUT) {
    u16* Cc = Cout + (size_t)c * NN;
    #pragma unroll
    for (int i = 0; i < 2; ++i) {
      const int rowg = m0 + w * 32 + i * 16 + quad * 4;
      #pragma unroll
      for (int j = 0; j < 4; ++j) {
        const int colg = n0 + j * 16 + r;
        #pragma unroll
        for (int g = 0; g < 4; ++g)
          Cc[(size_t)(rowg + g) * N2 + colg] = f2b(acc[i][j][g]);
      }
    }
  }
  // Column-sum partials over this block's 128 rows for its 64 cols.
  float s[4];
  #pragma unroll
  for (int j = 0; j < 4; ++j) {
    s[j] = 0.f;
    #pragma unroll
    for (int i = 0; i < 2; ++i)
      #pragma unroll
      for (int g = 0; g < 4; ++g) s[j] += acc[i][j][g];
    s[j] += __shfl_xor(s[j], 16);
    s[j] += __shfl_xor(s[j], 32);
  }
  __syncthreads();                 // MFMA-loop LDS reads done
  float* csl = (float*)SM;         // [4][64]
  if (quad == 0) {
    #pragma unroll
    for (int j = 0; j < 4; ++j) csl[w * 64 + j * 16 + r] = s[j];
  }
  __syncthreads();
  if (t < 64) {
    const float v = csl[t] + csl[64 + t] + csl[128 + t] + csl[192 + t];
    csp[((size_t)(c * 16) + blockIdx.y) * N2 + n0 + t] = v;
  }
  if constexpr (TOUT) {
    // Transpose tile via LDS (row stride 136 u16 = 272 B, 16-B aligned rows).
    // Each thread stores a FULL 32-u16 segment (4x uint4): 64 rows x 4 segs
    // x 32 u16 = 8192 = the whole 128x64 tile. (r7/r8 bug: only 2x uint4
    // stored -> half of H2t left unwritten.)
    __syncthreads();
    u16* tb = SM;                  // [64][136] u16 = 17.4 KB
    #pragma unroll
    for (int i = 0; i < 2; ++i) {
      #pragma unroll
      for (int j = 0; j < 4; ++j) {
        #pragma unroll
        for (int g = 0; g < 4; ++g)
          tb[(j * 16 + r) * 136 + (w * 32 + i * 16 + quad * 4 + g)] = f2b(acc[i][j][g]);
      }
    }
    __syncthreads();
    u16* Cc = Cout + (size_t)c * NN;
    const int rown = t >> 2, seg = t & 3;
    const u16* ps = tb + rown * 136 + seg * 32;
    uint4* pd = (uint4*)(Cc + (size_t)(n0 + rown) * N2 + m0 + seg * 32);
    pd[0] = ((const uint4*)ps)[0];
    pd[1] = ((const uint4*)ps)[1];
    pd[2] = ((const uint4*)ps)[2];
    pd[3] = ((const uint4*)ps)[3];
  }
}

// colinv[c][q] = (deg==0) ? 0 : 1/(deg+eps), deg = sum_s csp[c][s][q] - diag
__global__ void colinv_kernel(const float* __restrict__ csp, const float* __restrict__ diag, float* __restrict__ ci)
{
  const int idx = blockIdx.x * 256 + threadIdx.x;  // [0, 4096)
  float cs = 0.f;
  const int c = idx >> 11, q = idx & 2047;
  #pragma unroll
  for (int s = 0; s < 16; ++s) cs += csp[((size_t)(c * 16) + s) * N2 + q];
  const float deg = cs - diag[idx];
  ci[idx] = (deg == 0.f) ? 0.f : 1.f / (deg + 1e-8f);
}

// Hn[p][q] = bf16( p==q ? 0 : ci[q]*H[p][q] ), H bf16 in, bf16 out
__global__ __launch_bounds__(256) void scale_kernel(const u16* __restrict__ H, const float* __restrict__ ci, u16* __restrict__ Hn)
{
  const int idx = blockIdx.x * 256 + threadIdx.x;
  const int q0 = (idx & 255) * 8;
  const int p = (idx >> 8) & 2047;
  const int c = idx >> 19;
  const u16* src = H + (size_t)c * NN + (size_t)p * N2 + q0;
  const float* cv = ci + c * N2 + q0;
  uint4 hu = *(const uint4*)src;
  float h[8];
  h[0] = b2f_bits(hu.x << 16); h[1] = b2f_bits(hu.x & 0xffff0000u);
  h[2] = b2f_bits(hu.y << 16); h[3] = b2f_bits(hu.y & 0xffff0000u);
  h[4] = b2f_bits(hu.z << 16); h[5] = b2f_bits(hu.z & 0xffff0000u);
  h[6] = b2f_bits(hu.w << 16); h[7] = b2f_bits(hu.w & 0xffff0000u);
  float f[8];
  #pragma unroll
  for (int u = 0; u < 8; ++u) {
    float v = h[u] * cv[u];
    f[u] = (q0 + u == p) ? 0.f : v;
  }
  *(uint4*)(Hn + (size_t)c * NN + (size_t)p * N2 + q0) = pack8(f);
}

// ---------------------------------------------------------------------------
// T-partials via MFMA: Tp[split][c][i][k'] partial of sum_j H2t[i][j]*Xwt[k'][j]
// over j in split's 128-range. M=2048(i), N=64(k'), K=2048(j), K-split 16.
// Grid (16 m-tiles, 16 splits, 2 c) = 512 blocks.
// ---------------------------------------------------------------------------
__global__ __launch_bounds__(256) void tgemm_kernel(
    const u16* __restrict__ H2t, const u16* __restrict__ Xwt, float* __restrict__ Tp)
{
  const int c = blockIdx.z, split = blockIdx.y;
  const int m0 = blockIdx.x * 128;
  const u16* Ac = H2t + (size_t)c * NN;
  const int t = threadIdx.x, w = t >> 6, lane = t & 63;
  const int quad = lane >> 4, r = lane & 15;
  __shared__ u16 As[128 * 64];
  __shared__ u16 Bs[64 * 64];

  v4f zero4 = { 0.f, 0.f, 0.f, 0.f };
  v4f acc[2][4];
  #pragma unroll
  for (int i = 0; i < 2; ++i)
    #pragma unroll
    for (int j = 0; j < 4; ++j) acc[i][j] = zero4;

  const int srow = lane >> 3;
  const int sgran = (lane & 7) ^ srow;

  for (int kk = 0; kk < 2; ++kk) {
    const int kt = split * 128 + kk * 64;
    __syncthreads();
    #pragma unroll
    for (int i = 0; i < 4; ++i) {
      const int chunk = i * 4 + w;
      const u16* ga = Ac + (size_t)(m0 + chunk * 8 + srow) * N2 + kt + sgran * 8;
      __builtin_amdgcn_global_load_lds((guint*)ga, (luint*)(As + chunk * 512), 16, 0, 0);
    }
    #pragma unroll
    for (int i = 0; i < 2; ++i) {
      const int chunk = i * 4 + w;
      const u16* gb = Xwt + (size_t)(chunk * 8 + srow) * N2 + kt + sgran * 8;
      __builtin_amdgcn_global_load_lds((guint*)gb, (luint*)(Bs + chunk * 512), 16, 0, 0);
    }
    __syncthreads();
    #pragma unroll
    for (int ks = 0; ks < 2; ++ks) {
      const int sl = ((ks * 4 + quad) ^ (r & 7)) * 8;
      short8 af[2], bf[4];
      #pragma unroll
      for (int i = 0; i < 2; ++i)
        af[i] = *(const short8*)(As + (w * 32 + i * 16 + r) * 64 + sl);
      #pragma unroll
      for (int j = 0; j < 4; ++j)
        bf[j] = *(const short8*)(Bs + (j * 16 + r) * 64 + sl);
      #pragma unroll
      for (int i = 0; i < 2; ++i)
        #pragma unroll
        for (int j = 0; j < 4; ++j)
          acc[i][j] = __builtin_amdgcn_mfma_f32_16x16x32_bf16(af[i], bf[j], acc[i][j], 0, 0, 0);
    }
  }
  const size_t pbase = (size_t)(split * 2 + c) * 2048;
  #pragma unroll
  for (int i = 0; i < 2; ++i) {
    const int rowg = m0 + w * 32 + i * 16 + quad * 4;
    #pragma unroll
    for (int j = 0; j < 4; ++j) {
      const int colg = j * 16 + r;
      #pragma unroll
      for (int g = 0; g < 4; ++g)
        Tp[(pbase + rowg + g) * 64 + colg] = acc[i][j][g];
    }
  }
}

// out[i][c*64+k] = relu( dinv * (T - hd*xw + xw) ), fp32
__global__ void epilogue_kernel(const float* __restrict__ Tp, const float* __restrict__ cspb,
                                const float* __restrict__ diag2, const u16* __restrict__ Xwt,
                                float* __restrict__ out)
{
  const int idx = blockIdx.x * 256 + threadIdx.x;
  const int k = idx & 63;
  const int c = (idx >> 6) & 1;
  const int i = idx >> 7;
  float T = 0.f, cs = 0.f;
  #pragma unroll
  for (int s = 0; s < 16; ++s) {
    T  += Tp[((size_t)(s * 2 + c) * 2048 + i) * 64 + k];
    cs += cspb[((size_t)(c * 16) + s) * N2 + i];
  }
  const float hd = diag2[c * N2 + i];
  const float xw = b2f(Xwt[(size_t)k * N2 + i]);
  const float deg = cs - hd + 1.0f;  // add=True: diag set to 1 contributes +1
  const float dinv = (deg == 0.f) ? 0.f : 1.f / (deg + 1e-8f);
  float v = dinv * (T - hd * xw + xw);
  v = v > 0.f ? v : 0.f;
  out[(size_t)i * 128 + c * 64 + k] = v;
}

// ---------------------------------------------------------------------------
// Workspace layout (bytes), ~84.7 MB, all reads preceded by writes:
//   abf   @ 0          (16.78 MB bf16)  -- dead after gemm1
//   bbt   @ 16777216   (16.78 MB bf16)  -- dead after gemm1
//   a1t   @ 33554432   (16.78 MB bf16)  -- dead after gemm2
//   Hbf   @ 50331648   (16.78 MB bf16)  -- dead after scale
//   Hn    @ 67108864   (16.78 MB bf16)  -- dead after gemm2
//   Xwt   @ 83886080   (256 KB bf16 [64][2048])
//   cspa  @ 84148224   (256 KB)
//   cspb  @ 84410368   (256 KB)
//   diag1 @ 84672512   (16 KB)
//   diag2 @ 84688896   (16 KB)
//   ci1   @ 84705280   (16 KB)          -- end 84721664
//   H2t   @ 0          (16.78 MB bf16, over abf; written by gemm2<true>)
//   Tp    @ 16777216   (16.78 MB fp32 [16][2][2048][64], over bbt)
// ---------------------------------------------------------------------------
extern "C" void kernel_launch(void* const* d_in, const int* in_sizes, int n_in,
                              void* d_out, int out_size, void* d_ws, size_t ws_size,
                              hipStream_t stream) {
  const float* A  = (const float*)d_in[0];
  const float* X  = (const float*)d_in[1];
  const float* w1 = (const float*)d_in[2];
  const float* w2 = (const float*)d_in[3];
  const float* w3 = (const float*)d_in[4];
  const float* W  = (const float*)d_in[5];
  float* out = (float*)d_out;
  char* ws = (char*)d_ws;

  u16*   abf   = (u16*)(ws + 0);
  u16*   bbt   = (u16*)(ws + 16777216);
  u16*   a1t   = (u16*)(ws + 33554432);
  u16*   Hbf   = (u16*)(ws + 50331648);
  u16*   Hn    = (u16*)(ws + 67108864);
  u16*   Xwt   = (u16*)(ws + 83886080);
  float* cspa  = (float*)(ws + 84148224);
  float* cspb  = (float*)(ws + 84410368);
  float* diag1 = (float*)(ws + 84672512);
  float* diag2 = (float*)(ws + 84688896);
  float* ci1   = (float*)(ws + 84705280);
  u16*   H2t   = (u16*)(ws + 0);
  float* Tp    = (float*)(ws + 16777216);

  conv_kernel<<<dim3(64, 64), 256, 0, stream>>>(A, w1, w2, w3, X, W, abf, bbt, a1t, Xwt);
  gemm_kernel<false><<<dim3(32, 16, 2), 256, 0, stream>>>(abf, bbt, Hbf, cspa, diag1);
  colinv_kernel<<<16, 256, 0, stream>>>(cspa, diag1, ci1);
  scale_kernel<<<4096, 256, 0, stream>>>(Hbf, ci1, Hn);
  gemm_kernel<true><<<dim3(32, 16, 2), 256, 0, stream>>>(Hn, a1t, H2t, cspb, diag2);
  tgemm_kernel<<<dim3(16, 16, 2), 256, 0, stream>>>(H2t, Xwt, Tp);
  epilogue_kernel<<<1024, 256, 0, stream>>>(Tp, cspb, diag2, Xwt, out);
}